// Round 1
// baseline (2482.402 us; speedup 1.0000x reference)
//
#include <hip/hip_runtime.h>
#include <hip/hip_bf16.h>
#include <cstdint>
#include <cstddef>

#define VOCAB 10000
#define EMB   1024
#define HID   1024
#define BATCH 32
#define SEQ   256
#define ROWS  (SEQ*BATCH)   // 8192
#define NBLK  64            // scan blocks; 16 cols each

typedef __attribute__((ext_vector_type(8))) short short8;
typedef __attribute__((ext_vector_type(4))) float f32x4;

static __device__ __forceinline__ unsigned short f2bf(float f){
  unsigned int u = __builtin_bit_cast(unsigned int, f);
  u += 0x7fffu + ((u >> 16) & 1u);
  return (unsigned short)(u >> 16);
}

// ---------- transpose-convert: fp32 src[K][N] -> bf16 dst[N][K] ----------
__global__ void k_transpose(const float* __restrict__ src, unsigned short* __restrict__ dst,
                            int K, int N){
  __shared__ unsigned short tile[64][65];
  int n0 = blockIdx.x * 64, k0 = blockIdx.y * 64;
  int tid = threadIdx.x;
  #pragma unroll
  for (int it = 0; it < 16; ++it){
    int e = tid + it*256;
    int i = e >> 6, j = e & 63;          // i: k-offset, j: n-offset (coalesced on j)
    float v = 0.f;
    if (k0 + i < K && n0 + j < N) v = src[(size_t)(k0+i)*N + n0 + j];
    tile[j][i] = f2bf(v);
  }
  __syncthreads();
  #pragma unroll
  for (int it = 0; it < 16; ++it){
    int e = tid + it*256;
    int r = e >> 6, c = e & 63;          // r: n-offset, c: k-offset (coalesced on c)
    if (n0 + r < N && k0 + c < K)
      dst[(size_t)(n0+r)*K + k0 + c] = tile[r][c];
  }
}

// ---------- embedding gather + fp32->bf16 : X[t*32+b][e] ----------
__global__ void k_gather(const int* __restrict__ seq, const float* __restrict__ emb,
                         unsigned short* __restrict__ X){
  int r = blockIdx.x;                 // r = t*32 + b
  int t = r >> 5, b = r & 31;
  int idx = seq[b*SEQ + t];
  const float4* s = (const float4*)(emb + (size_t)idx * EMB);
  float4 v = s[threadIdx.x];
  ushort4 o;
  o.x = f2bf(v.x); o.y = f2bf(v.y); o.z = f2bf(v.z); o.w = f2bf(v.w);
  ((ushort4*)(X + (size_t)r * EMB))[threadIdx.x] = o;
}

// ---------- GEMM: C[M][ldc] = A[M][K](bf16) * BT[Npad][K](bf16)^T + bias ----------
// 128x128 tile, BK=32, 4 waves of 64x64, mfma_f32_16x16x32_bf16.
template<bool OUT_BF16>
__global__ __launch_bounds__(256) void k_gemm_bt(
    const unsigned short* __restrict__ A,
    const unsigned short* __restrict__ BT,
    const float* __restrict__ bias,
    void* __restrict__ C, int M, int Nreal, int K, int ldc){
  __shared__ __align__(16) unsigned short As[128][40];
  __shared__ __align__(16) unsigned short Bs[128][40];
  int tid  = threadIdx.x;
  int lane = tid & 63, wid = tid >> 6;
  int wr = (wid >> 1) * 64, wc = (wid & 1) * 64;
  int m0 = blockIdx.y * 128, n0 = blockIdx.x * 128;
  int la = lane & 15, ko = (lane >> 4) * 8;
  f32x4 acc[4][4] = {};
  for (int k0 = 0; k0 < K; k0 += 32){
    #pragma unroll
    for (int q = tid; q < 512; q += 256){
      int row = q >> 2, kc = (q & 3) * 8;
      *(uint4*)&As[row][kc] = *(const uint4*)(A  + (size_t)(m0+row)*K + k0 + kc);
      *(uint4*)&Bs[row][kc] = *(const uint4*)(BT + (size_t)(n0+row)*K + k0 + kc);
    }
    __syncthreads();
    short8 av[4], bv[4];
    #pragma unroll
    for (int f = 0; f < 4; ++f){
      av[f] = *(const short8*)&As[wr + f*16 + la][ko];
      bv[f] = *(const short8*)&Bs[wc + f*16 + la][ko];
    }
    #pragma unroll
    for (int mf = 0; mf < 4; ++mf)
      #pragma unroll
      for (int nf = 0; nf < 4; ++nf)
        acc[mf][nf] = __builtin_amdgcn_mfma_f32_16x16x32_bf16(av[mf], bv[nf], acc[mf][nf], 0, 0, 0);
    __syncthreads();
  }
  int dr = (lane >> 4) * 4, dc = lane & 15;
  #pragma unroll
  for (int mf = 0; mf < 4; ++mf){
    #pragma unroll
    for (int nf = 0; nf < 4; ++nf){
      int col = n0 + wc + nf*16 + dc;
      if (col >= Nreal) continue;
      float bb = bias[col];
      #pragma unroll
      for (int rg = 0; rg < 4; ++rg){
        int row = m0 + wr + mf*16 + dr + rg;
        float v = acc[mf][nf][rg] + bb;
        if (OUT_BF16) ((unsigned short*)C)[(size_t)row*ldc + col] = f2bf(v);
        else          ((float*)C)[(size_t)row*ldc + col] = v;
      }
    }
  }
}

// ---------- persistent scan: 64 blocks, each owns 16 columns of h/c ----------
// g[:,cols] = G0[t][:,cols] + h_{t-1} @ U[:,cols]; gates; h_t written to Hfull.
__global__ __launch_bounds__(256) void k_scan(
    const unsigned short* __restrict__ UT,   // [HID][HID] bf16, UT[n][k] = w_gate[EMB+k][n]
    const float* __restrict__ G0,            // [ROWS][HID] fp32 (includes b_gate)
    unsigned short* Hfull,                   // [(32+ROWS)][HID] bf16, rows 0..31 zeroed
    int* counter){
  __shared__ __align__(16) unsigned short UTs[16][1032];
  __shared__ float red[4][32][16];
  __shared__ float c_lds[32][16];
  int tid  = threadIdx.x;
  int bid  = blockIdx.x;
  int n0   = bid * 16;
  int lane = tid & 63, wid = tid >> 6;

  { // preload U slice (16 cols x 1024 k) into LDS once
    int row = tid >> 4, chunk = tid & 15;
    const uint4* src = (const uint4*)(UT + (size_t)(n0+row)*HID + chunk*64);
    uint4* dst = (uint4*)&UTs[row][chunk*64];
    #pragma unroll
    for (int j = 0; j < 8; ++j) dst[j] = src[j];
  }
  for (int o = tid; o < 512; o += 256) c_lds[o>>4][o&15] = 0.f;
  __syncthreads();

  int kq = wid * 256;                      // each wave owns a K-quarter
  int la = lane & 15, ko = (lane >> 4) * 8;
  int dr = (lane >> 4) * 4, dc = lane & 15;

  for (int t = 0; t < SEQ; ++t){
    const unsigned short* hprev = Hfull + (size_t)t * 32 * HID;  // h_{t-1} (zeros at t=0)
    f32x4 acc0 = {0,0,0,0}, acc1 = {0,0,0,0};
    #pragma unroll
    for (int ks = 0; ks < 8; ++ks){
      int k = kq + ks*32 + ko;
      short8 a0 = *(const short8*)(hprev + (size_t)la        * HID + k);
      short8 a1 = *(const short8*)(hprev + (size_t)(16 + la) * HID + k);
      short8 bv = *(const short8*)&UTs[la][k];
      acc0 = __builtin_amdgcn_mfma_f32_16x16x32_bf16(a0, bv, acc0, 0, 0, 0);
      acc1 = __builtin_amdgcn_mfma_f32_16x16x32_bf16(a1, bv, acc1, 0, 0, 0);
    }
    #pragma unroll
    for (int rg = 0; rg < 4; ++rg){
      red[wid][dr + rg][dc]      = acc0[rg];
      red[wid][16 + dr + rg][dc] = acc1[rg];
    }
    __syncthreads();
    #pragma unroll
    for (int o = tid; o < 512; o += 256){
      int b = o >> 4, n = o & 15;
      float g = red[0][b][n] + red[1][b][n] + red[2][b][n] + red[3][b][n]
              + G0[((size_t)t*32 + b)*HID + n0 + n];
      float s  = 1.f / (1.f + expf(-g));
      float tg = tanhf(g);
      float c  = c_lds[b][n];
      float cn = c*s + tg*s;
      float hn = tanhf(cn) * s;
      c_lds[b][n] = cn;
      Hfull[((size_t)(t+1)*32 + b)*HID + n0 + n] = f2bf(hn);
    }
    __syncthreads();                      // all H-writes issued, red/c consumed
    if (tid == 0){
      __threadfence();                    // agent-scope release of h-writes
      __hip_atomic_fetch_add(counter, 1, __ATOMIC_RELAXED, __HIP_MEMORY_SCOPE_AGENT);
      int target = NBLK * (t + 1);
      while (__hip_atomic_load(counter, __ATOMIC_ACQUIRE, __HIP_MEMORY_SCOPE_AGENT) < target)
        __builtin_amdgcn_s_sleep(2);
      __threadfence();                    // acquire: invalidate caches before h-reads
    }
    __syncthreads();
  }
}

extern "C" void kernel_launch(void* const* d_in, const int* in_sizes, int n_in,
                              void* d_out, int out_size, void* d_ws, size_t ws_size,
                              hipStream_t stream){
  (void)in_sizes; (void)n_in; (void)out_size;
  const int*   seq     = (const int*)d_in[0];
  const float* emb     = (const float*)d_in[1];
  const float* w_gate  = (const float*)d_in[2];
  const float* b_gate  = (const float*)d_in[3];
  const float* w_out   = (const float*)d_in[4];
  const float* b_out   = (const float*)d_in[5];
  const float* w_dense = (const float*)d_in[6];
  const float* b_dense = (const float*)d_in[7];
  float* out = (float*)d_out;

  const int NPAD_D = 10112;   // 79 * 128
  char* ws = (char*)d_ws;
  size_t off = 0;
  auto alloc = [&](size_t bytes){ size_t o = off; off += (bytes + 255) & ~(size_t)255; return o; };
  size_t off_W1T = alloc((size_t)2*HID*HID);              // bf16 [1024][1024]
  size_t off_UT  = alloc((size_t)2*HID*HID);
  size_t off_WoT = alloc((size_t)2*HID*HID);
  size_t off_WdT = alloc((size_t)2*NPAD_D*HID);           // bf16 [10112][1024]
  size_t off_X   = alloc((size_t)2*ROWS*EMB);             // bf16 [8192][1024]; reused as YS
  size_t off_G0  = alloc((size_t)4*ROWS*HID);             // fp32 [8192][1024]
  size_t off_H   = alloc((size_t)2*(ROWS+32)*HID);        // bf16 [8224][1024]
  size_t off_cnt = alloc(256);
  if (ws_size < off) return;  // workspace too small -> visible failure, no corruption

  unsigned short* W1T = (unsigned short*)(ws + off_W1T);
  unsigned short* UT  = (unsigned short*)(ws + off_UT);
  unsigned short* WoT = (unsigned short*)(ws + off_WoT);
  unsigned short* WdT = (unsigned short*)(ws + off_WdT);
  unsigned short* X   = (unsigned short*)(ws + off_X);
  unsigned short* YS  = (unsigned short*)(ws + off_X);    // reuse after G0 GEMM
  float*          G0  = (float*)(ws + off_G0);
  unsigned short* Hf  = (unsigned short*)(ws + off_H);
  int*            cnt = (int*)(ws + off_cnt);

  // init: barrier counter, WdT zero-pad rows (10000..10111), Hfull rows 0..31 (h_{-1}=0)
  hipMemsetAsync(cnt, 0, sizeof(int), stream);
  hipMemsetAsync(WdT + (size_t)10000*HID, 0, (size_t)2*(NPAD_D-10000)*HID, stream);
  hipMemsetAsync(Hf, 0, (size_t)2*32*HID, stream);

  // weight transposes (fp32 [K][N] -> bf16 [N][K])
  k_transpose<<<dim3(16,16), 256, 0, stream>>>(w_gate,             W1T, HID, HID);
  k_transpose<<<dim3(16,16), 256, 0, stream>>>(w_gate + HID*HID,   UT,  HID, HID);
  k_transpose<<<dim3(16,16), 256, 0, stream>>>(w_out,              WoT, HID, HID);
  k_transpose<<<dim3(157,16),256, 0, stream>>>(w_dense,            WdT, HID, VOCAB);

  // embedding gather
  k_gather<<<ROWS, 256, 0, stream>>>(seq, emb, X);

  // G0 = X @ W1 + b_gate  (fp32 out)
  k_gemm_bt<false><<<dim3(8,64), 256, 0, stream>>>(X, W1T, b_gate, G0, ROWS, HID, EMB, HID);

  // sequential scan (persistent cooperative-style kernel)
  k_scan<<<NBLK, 256, 0, stream>>>(UT, G0, Hf, cnt);

  // ys = H @ w_out + b_out  (bf16 out, into X region)
  k_gemm_bt<true><<<dim3(8,64), 256, 0, stream>>>(Hf + (size_t)32*HID, WoT, b_out, YS,
                                                  ROWS, HID, HID, HID);

  // logits = ys @ w_dense + b_dense (fp32 out)
  k_gemm_bt<false><<<dim3(79,64), 256, 0, stream>>>(YS, WdT, b_dense, out,
                                                    ROWS, VOCAB, HID, VOCAB);
}